// Round 1
// baseline (34.542 us; speedup 1.0000x reference)
//
#include <hip/hip_runtime.h>

// out[i] = MLP(emb_user[uid[i]]) + MLP(emb_movie[mid[i]])
// MLP: relu(x@W1+b1) -> relu(@W2+b2) -> @W3+b3.  All GEMMs via bf16 MFMA
// (16x16x32), fp32 accumulate.  Swapped operands: compute h^T = W^T @ x^T so
// the C-layout register quad (4 consecutive output rows) packs to one b64 LDS
// write of h row-major, which is exactly the next layer's B-fragment (b128).
//
// Per block (256 thr = 4 waves): stage W1^T [256][72] and W2^T [128][264] as
// bf16 in LDS (pads chosen so all frag reads/writes hit the bank-access
// minimum).  Each wave handles 32 samples/chunk as 4 m-tiles (2 user + 2
// movie 16-row tiles) so every weight-frag read feeds 4 MFMAs.  h1 is
// wave-private ([4][16][72] per wave, K-quarter split) -> no barriers in the
// main loop.  Biases folded into accumulator init.  Layer 3 = per-lane dot +
// shfl_xor(16,32) reduce; lanes 0..31 write out = p_user + p_movie.

typedef __attribute__((ext_vector_type(8))) short bf16x8;
typedef __attribute__((ext_vector_type(4))) float f32x4;

__device__ __forceinline__ unsigned short f2bf(float f) {
  unsigned int u = __builtin_bit_cast(unsigned int, f);
  u = u + 0x7fffu + ((u >> 16) & 1u);  // RNE
  return (unsigned short)(u >> 16);
}

struct __align__(16) LdsLayout {
  unsigned short w1t[256 * 72];        // W1^T [n1][k], pad 64->72   (36864 B)
  unsigned short w2t[128 * 264];       // W2^T [n2][k], pad 256->264 (67584 B)
  unsigned short h1[4 * 4 * 16 * 72];  // per-wave [4 mt][16 m][72]  (36864 B)
};                                      // total 141312 B -> 1 block/CU

__global__ __launch_bounds__(256, 1) void movielens_mlp(
    const int* __restrict__ uids, const int* __restrict__ mids,
    const float* __restrict__ EU, const float* __restrict__ EM,
    const float* __restrict__ W1, const float* __restrict__ B1,
    const float* __restrict__ W2, const float* __restrict__ B2,
    const float* __restrict__ W3, const float* __restrict__ B3,
    float* __restrict__ out) {
  __shared__ LdsLayout L;
  const int tid = threadIdx.x;

  // ---- stage weights as bf16, transposed (coalesced global reads) ----
  {
    const int n1 = tid;  // 0..255
#pragma unroll 4
    for (int k = 0; k < 64; ++k)
      L.w1t[n1 * 72 + k] = f2bf(W1[k * 256 + n1]);
    const int n2 = tid & 127, kh = (tid >> 7) * 128;
#pragma unroll 4
    for (int k2 = 0; k2 < 128; ++k2) {
      const int k = kh + k2;
      L.w2t[n2 * 264 + k] = f2bf(W2[k * 128 + n2]);
    }
  }
  __syncthreads();

  const int lane = tid & 63;
  const int wv = tid >> 6;
  const int m = lane & 15;   // sample-in-tile / frag row
  const int g = lane >> 4;   // k-group 0..3
  unsigned short* __restrict__ h1 = &L.h1[wv * 4608];

  const float b3v = B3[0];

  for (int chunk = 0; chunk < 2; ++chunk) {
    const int sbase = blockIdx.x * 256 + chunk * 128 + wv * 32;
    const int su = sbase + m, sv = sbase + 16 + m;
    const float* rp[4];
    rp[0] = EU + (size_t)uids[su] * 64;
    rp[1] = EU + (size_t)uids[sv] * 64;
    rp[2] = EM + (size_t)mids[su] * 64;
    rp[3] = EM + (size_t)mids[sv] * 64;

    // gather x B-frags: lane holds x[sample m][k = 32*kt + 8g .. +7]
    bf16x8 xf[4][2];
#pragma unroll
    for (int mt = 0; mt < 4; ++mt) {
#pragma unroll
      for (int kt = 0; kt < 2; ++kt) {
        const float4 a = *(const float4*)(rp[mt] + kt * 32 + 8 * g);
        const float4 b = *(const float4*)(rp[mt] + kt * 32 + 8 * g + 4);
        bf16x8 t;
        t[0] = (short)f2bf(a.x); t[1] = (short)f2bf(a.y);
        t[2] = (short)f2bf(a.z); t[3] = (short)f2bf(a.w);
        t[4] = (short)f2bf(b.x); t[5] = (short)f2bf(b.y);
        t[6] = (short)f2bf(b.z); t[7] = (short)f2bf(b.w);
        xf[mt][kt] = t;
      }
    }

    // layer-2 accumulators, bias-initialized (lane holds h2^T rows 16nt2+4g+r)
    f32x4 acc2[4][8];
#pragma unroll
    for (int nt2 = 0; nt2 < 8; ++nt2) {
      const float4 bv = *(const float4*)(B2 + nt2 * 16 + 4 * g);
#pragma unroll
      for (int mt = 0; mt < 4; ++mt) {
        acc2[mt][nt2][0] = bv.x; acc2[mt][nt2][1] = bv.y;
        acc2[mt][nt2][2] = bv.z; acc2[mt][nt2][3] = bv.w;
      }
    }

#pragma unroll
    for (int q = 0; q < 4; ++q) {
      // ---- layer-1 quarter: n1 in [64q, 64q+64) -> h1 local k [0,64) ----
#pragma unroll
      for (int nt = 0; nt < 4; ++nt) {
        const int n1 = q * 64 + nt * 16;
        const bf16x8 wa0 = *(const bf16x8*)&L.w1t[(n1 + m) * 72 + 8 * g];
        const bf16x8 wa1 = *(const bf16x8*)&L.w1t[(n1 + m) * 72 + 32 + 8 * g];
        const float4 b1v = *(const float4*)(B1 + n1 + 4 * g);
#pragma unroll
        for (int mt = 0; mt < 4; ++mt) {
          f32x4 acc;
          acc[0] = b1v.x; acc[1] = b1v.y; acc[2] = b1v.z; acc[3] = b1v.w;
          acc = __builtin_amdgcn_mfma_f32_16x16x32_bf16(wa0, xf[mt][0], acc, 0, 0, 0);
          acc = __builtin_amdgcn_mfma_f32_16x16x32_bf16(wa1, xf[mt][1], acc, 0, 0, 0);
          // lane holds h1[m][n1loc = 16nt + 4g + r], r=0..3 -> one b64 write
          const unsigned int lo =
              (unsigned int)f2bf(fmaxf(acc[0], 0.f)) |
              ((unsigned int)f2bf(fmaxf(acc[1], 0.f)) << 16);
          const unsigned int hi =
              (unsigned int)f2bf(fmaxf(acc[2], 0.f)) |
              ((unsigned int)f2bf(fmaxf(acc[3], 0.f)) << 16);
          uint2 pk; pk.x = lo; pk.y = hi;
          *(uint2*)&h1[mt * 1152 + m * 72 + nt * 16 + 4 * g] = pk;
        }
      }
      // ---- layer-2 partial over this k-quarter ----
      bf16x8 hf[4][2];
#pragma unroll
      for (int mt = 0; mt < 4; ++mt)
#pragma unroll
        for (int kt = 0; kt < 2; ++kt)
          hf[mt][kt] = *(const bf16x8*)&h1[mt * 1152 + m * 72 + kt * 32 + 8 * g];
#pragma unroll
      for (int nt2 = 0; nt2 < 8; ++nt2) {
        const bf16x8 w20 = *(const bf16x8*)&L.w2t[(nt2 * 16 + m) * 264 + q * 64 + 8 * g];
        const bf16x8 w21 = *(const bf16x8*)&L.w2t[(nt2 * 16 + m) * 264 + q * 64 + 32 + 8 * g];
#pragma unroll
        for (int mt = 0; mt < 4; ++mt) {
          acc2[mt][nt2] = __builtin_amdgcn_mfma_f32_16x16x32_bf16(w20, hf[mt][0], acc2[mt][nt2], 0, 0, 0);
          acc2[mt][nt2] = __builtin_amdgcn_mfma_f32_16x16x32_bf16(w21, hf[mt][1], acc2[mt][nt2], 0, 0, 0);
        }
      }
    }

    // ---- layer 3: relu(h2) . W3, reduce over n2 across lane groups ----
    float part[4] = {0.f, 0.f, 0.f, 0.f};
#pragma unroll
    for (int nt2 = 0; nt2 < 8; ++nt2) {
      const float4 w3v = *(const float4*)(W3 + nt2 * 16 + 4 * g);
#pragma unroll
      for (int mt = 0; mt < 4; ++mt) {
        const f32x4 c = acc2[mt][nt2];
        part[mt] += fmaxf(c[0], 0.f) * w3v.x + fmaxf(c[1], 0.f) * w3v.y +
                    fmaxf(c[2], 0.f) * w3v.z + fmaxf(c[3], 0.f) * w3v.w;
      }
    }
#pragma unroll
    for (int mt = 0; mt < 4; ++mt) {
      part[mt] += __shfl_xor(part[mt], 16, 64);
      part[mt] += __shfl_xor(part[mt], 32, 64);
    }
    if (lane < 16) {
      out[sbase + lane] = part[0] + part[2] + 2.f * b3v;
    } else if (lane < 32) {
      out[sbase + lane] = part[1] + part[3] + 2.f * b3v;  // sample sbase+16+(lane-16)
    }
  }
}

extern "C" void kernel_launch(void* const* d_in, const int* in_sizes, int n_in,
                              void* d_out, int out_size, void* d_ws, size_t ws_size,
                              hipStream_t stream) {
  const int* uids = (const int*)d_in[0];
  const int* mids = (const int*)d_in[1];
  const float* EU = (const float*)d_in[2];
  const float* EM = (const float*)d_in[3];
  const float* W1 = (const float*)d_in[4];
  const float* B1 = (const float*)d_in[5];
  const float* W2 = (const float*)d_in[6];
  const float* B2 = (const float*)d_in[7];
  const float* W3 = (const float*)d_in[8];
  const float* B3 = (const float*)d_in[9];
  float* out = (float*)d_out;

  const int B = in_sizes[0];       // 65536
  const int nblk = B / 256;        // 256 samples per block
  hipLaunchKernelGGL(movielens_mlp, dim3(nblk), dim3(256), 0, stream,
                     uids, mids, EU, EM, W1, B1, W2, B2, W3, B3, out);
}

// Round 2
// 25.955 us; speedup vs baseline: 1.3309x; 1.3309x over previous
//
#include <hip/hip_runtime.h>

// out[i] = MLP(emb_user[uid[i]]) + MLP(emb_movie[mid[i]])
// MLP: relu(x@W1+b1) -> relu(@W2+b2) -> @W3+b3, bf16 MFMA 16x16x32, fp32 acc.
//
// All LDS data is stored in MFMA-FRAGMENT ORDER: one fragment = 64 lanes x 16B
// = 1KB contiguous, read as base + lane*16 (conflict-free by construction).
//   w1f[nt(16)][kt(2)]   : A-frag of W1^T tile nt, K-chunk kt      (32 KB)
//   w2f[nt2(8)][hq(8)]   : A-frag of W2^T tile nt2, K-chunk hq     (64 KB)
//   h1f[wave(8)][mt(4)]  : B-frag of h1 for current 32-ch chunk    (32 KB)
// Layer-1 output quads are written straight into B-frag order via the mapping
//   channel c=16*ntloc+4g+r, sample m  ->  slot (2*ntloc+(g>>1))*16+m,
//   byte 8*(g&1)+2r   (b64 write, 4 dwords/bank = minimal).
// 512 thr = 8 waves, each wave owns 32 samples (4 m-tiles: 2 user + 2 movie).
// K of layer 2 streamed in 8 chunks of 32 (hq); h1 buffer is wave-private so
// the main loop has NO barriers.  LDS total 128 KB; __launch_bounds__(512,2)
// keeps VGPR<=256 -> 2 waves/SIMD.

typedef __attribute__((ext_vector_type(8))) short bf16x8;
typedef __attribute__((ext_vector_type(4))) float f32x4;

__device__ __forceinline__ unsigned int bfr(float f) {   // RNE bf16 in low 16
  unsigned int u = __builtin_bit_cast(unsigned int, f);
  return (u + 0x7fffu + ((u >> 16) & 1u)) >> 16;
}
__device__ __forceinline__ unsigned int bfrh(float f) {  // RNE bf16 in high 16
  unsigned int u = __builtin_bit_cast(unsigned int, f);
  return (u + 0x7fffu + ((u >> 16) & 1u)) & 0xffff0000u;
}
__device__ __forceinline__ unsigned int pk2(float lo, float hi) {
  return bfr(lo) | bfrh(hi);
}

__global__ __launch_bounds__(512, 2) void movielens_mlp(
    const int* __restrict__ uids, const int* __restrict__ mids,
    const float* __restrict__ EU, const float* __restrict__ EM,
    const float* __restrict__ W1, const float* __restrict__ B1,
    const float* __restrict__ W2, const float* __restrict__ B2,
    const float* __restrict__ W3, const float* __restrict__ B3,
    float* __restrict__ out) {
  __shared__ __align__(16) unsigned short w1f[16 * 2 * 512];  // 32 KB
  __shared__ __align__(16) unsigned short w2f[8 * 8 * 512];   // 64 KB
  __shared__ __align__(16) unsigned short h1f[8 * 4 * 512];   // 32 KB

  const int tid = threadIdx.x;  // 0..511

  // ---------------- stage weights into fragment order ----------------
  {
    // W1 [64][256]: 16 k-quads, 64 threads each (float4 over n), 2 passes.
    const int u = tid & 63;
#pragma unroll
    for (int pass = 0; pass < 2; ++pass) {
      const int qd = (tid >> 6) + 8 * pass;  // k-quad 0..15
      const float* src = W1 + (qd * 4) * 256 + 4 * u;
      const float4 r0 = *(const float4*)(src);
      const float4 r1 = *(const float4*)(src + 256);
      const float4 r2 = *(const float4*)(src + 512);
      const float4 r3 = *(const float4*)(src + 768);
      const float c0[4] = {r0.x, r0.y, r0.z, r0.w};
      const float c1[4] = {r1.x, r1.y, r1.z, r1.w};
      const float c2[4] = {r2.x, r2.y, r2.z, r2.w};
      const float c3[4] = {r3.x, r3.y, r3.z, r3.w};
      const int kt = qd >> 3, g = (qd >> 1) & 3, bo = (qd & 1) * 4;
#pragma unroll
      for (int p = 0; p < 4; ++p) {
        const int n = 4 * u + p, nt = n >> 4, mm = n & 15;
        uint2 pk;
        pk.x = pk2(c0[p], c1[p]);
        pk.y = pk2(c2[p], c3[p]);
        *(uint2*)&w1f[(nt * 2 + kt) * 512 + (g * 16 + mm) * 8 + bo] = pk;
      }
    }
    // W2 [256][128]: 64 k-quads, 32 threads each, 4 passes.
    const int u2 = tid & 31;
#pragma unroll
    for (int pass = 0; pass < 4; ++pass) {
      const int qd = (tid >> 5) + 16 * pass;  // k-quad 0..63
      const float* src = W2 + (qd * 4) * 128 + 4 * u2;
      const float4 r0 = *(const float4*)(src);
      const float4 r1 = *(const float4*)(src + 128);
      const float4 r2 = *(const float4*)(src + 256);
      const float4 r3 = *(const float4*)(src + 384);
      const float c0[4] = {r0.x, r0.y, r0.z, r0.w};
      const float c1[4] = {r1.x, r1.y, r1.z, r1.w};
      const float c2[4] = {r2.x, r2.y, r2.z, r2.w};
      const float c3[4] = {r3.x, r3.y, r3.z, r3.w};
      const int hq = qd >> 3, g = (qd >> 1) & 3, bo = (qd & 1) * 4;
#pragma unroll
      for (int p = 0; p < 4; ++p) {
        const int n = 4 * u2 + p, nt2 = n >> 4, mm = n & 15;
        uint2 pk;
        pk.x = pk2(c0[p], c1[p]);
        pk.y = pk2(c2[p], c3[p]);
        *(uint2*)&w2f[(nt2 * 8 + hq) * 512 + (g * 16 + mm) * 8 + bo] = pk;
      }
    }
  }
  __syncthreads();

  // ---------------- per-wave main work ----------------
  const int lane = tid & 63;
  const int wv = tid >> 6;      // 0..7
  const int m = lane & 15;
  const int g = lane >> 4;
  unsigned short* __restrict__ h1 = &h1f[wv * 4 * 512];

  const int sbase = blockIdx.x * 256 + wv * 32;
  const int su = sbase + m, sv = su + 16;

  const float* rp[4];
  rp[0] = EU + (size_t)uids[su] * 64;
  rp[1] = EU + (size_t)uids[sv] * 64;
  rp[2] = EM + (size_t)mids[su] * 64;
  rp[3] = EM + (size_t)mids[sv] * 64;

  // gather x B-frags: lane holds x[sample m][k = 32*kt + 8g .. +7]
  bf16x8 xf[4][2];
#pragma unroll
  for (int mt = 0; mt < 4; ++mt) {
#pragma unroll
    for (int kt = 0; kt < 2; ++kt) {
      const float4 a = *(const float4*)(rp[mt] + kt * 32 + 8 * g);
      const float4 b = *(const float4*)(rp[mt] + kt * 32 + 8 * g + 4);
      uint4 t;
      t.x = pk2(a.x, a.y);
      t.y = pk2(a.z, a.w);
      t.z = pk2(b.x, b.y);
      t.w = pk2(b.z, b.w);
      xf[mt][kt] = __builtin_bit_cast(bf16x8, t);
    }
  }

  // layer-2 accumulators, bias-initialized (lane holds h2^T row 16nt2+4g+r)
  f32x4 acc2[4][8];
#pragma unroll
  for (int nt2 = 0; nt2 < 8; ++nt2) {
    const float4 bv = *(const float4*)(B2 + nt2 * 16 + 4 * g);
#pragma unroll
    for (int mt = 0; mt < 4; ++mt) {
      acc2[mt][nt2][0] = bv.x; acc2[mt][nt2][1] = bv.y;
      acc2[mt][nt2][2] = bv.z; acc2[mt][nt2][3] = bv.w;
    }
  }

#pragma unroll 2
  for (int hq = 0; hq < 8; ++hq) {
    // ---- layer-1: produce 32 channels (2 n1-tiles) into h1 B-frags ----
#pragma unroll
    for (int ntloc = 0; ntloc < 2; ++ntloc) {
      const int fb = (hq * 4 + ntloc * 2) * 512;
      const bf16x8 wa0 = *(const bf16x8*)&w1f[fb + lane * 8];
      const bf16x8 wa1 = *(const bf16x8*)&w1f[fb + 512 + lane * 8];
      const float4 b1v = *(const float4*)(B1 + hq * 32 + ntloc * 16 + 4 * g);
      const int slot = (2 * ntloc + (g >> 1)) * 16 + m;
      const int wo = slot * 8 + (g & 1) * 4;
#pragma unroll
      for (int mt = 0; mt < 4; ++mt) {
        f32x4 acc;
        acc[0] = b1v.x; acc[1] = b1v.y; acc[2] = b1v.z; acc[3] = b1v.w;
        acc = __builtin_amdgcn_mfma_f32_16x16x32_bf16(wa0, xf[mt][0], acc, 0, 0, 0);
        acc = __builtin_amdgcn_mfma_f32_16x16x32_bf16(wa1, xf[mt][1], acc, 0, 0, 0);
        uint2 pk;
        pk.x = pk2(fmaxf(acc[0], 0.f), fmaxf(acc[1], 0.f));
        pk.y = pk2(fmaxf(acc[2], 0.f), fmaxf(acc[3], 0.f));
        *(uint2*)&h1[mt * 512 + wo] = pk;
      }
    }
    // ---- layer-2 partial over these 32 channels ----
    bf16x8 hf[4];
#pragma unroll
    for (int mt = 0; mt < 4; ++mt)
      hf[mt] = *(const bf16x8*)&h1[mt * 512 + lane * 8];
#pragma unroll
    for (int nt2 = 0; nt2 < 8; ++nt2) {
      const bf16x8 w2v = *(const bf16x8*)&w2f[(nt2 * 8 + hq) * 512 + lane * 8];
#pragma unroll
      for (int mt = 0; mt < 4; ++mt)
        acc2[mt][nt2] = __builtin_amdgcn_mfma_f32_16x16x32_bf16(w2v, hf[mt], acc2[mt][nt2], 0, 0, 0);
    }
  }

  // ---- layer 3: relu(h2) . W3, reduce over g-groups ----
  const float b3v = B3[0];
  float part[4] = {0.f, 0.f, 0.f, 0.f};
#pragma unroll
  for (int nt2 = 0; nt2 < 8; ++nt2) {
    const float4 w3v = *(const float4*)(W3 + nt2 * 16 + 4 * g);
#pragma unroll
    for (int mt = 0; mt < 4; ++mt) {
      const f32x4 c = acc2[mt][nt2];
      part[mt] += fmaxf(c[0], 0.f) * w3v.x + fmaxf(c[1], 0.f) * w3v.y +
                  fmaxf(c[2], 0.f) * w3v.z + fmaxf(c[3], 0.f) * w3v.w;
    }
  }
#pragma unroll
  for (int mt = 0; mt < 4; ++mt) {
    part[mt] += __shfl_xor(part[mt], 16, 64);
    part[mt] += __shfl_xor(part[mt], 32, 64);
  }
  if (lane < 16) {
    out[sbase + lane] = part[0] + part[2] + 2.f * b3v;
  } else if (lane < 32) {
    out[sbase + lane] = part[1] + part[3] + 2.f * b3v;
  }
}

extern "C" void kernel_launch(void* const* d_in, const int* in_sizes, int n_in,
                              void* d_out, int out_size, void* d_ws, size_t ws_size,
                              hipStream_t stream) {
  const int* uids = (const int*)d_in[0];
  const int* mids = (const int*)d_in[1];
  const float* EU = (const float*)d_in[2];
  const float* EM = (const float*)d_in[3];
  const float* W1 = (const float*)d_in[4];
  const float* B1 = (const float*)d_in[5];
  const float* W2 = (const float*)d_in[6];
  const float* B2 = (const float*)d_in[7];
  const float* W3 = (const float*)d_in[8];
  const float* B3 = (const float*)d_in[9];
  float* out = (float*)d_out;

  const int B = in_sizes[0];  // 65536
  const int nblk = B / 256;   // 256 blocks, 256 samples each
  hipLaunchKernelGGL(movielens_mlp, dim3(nblk), dim3(512), 0, stream,
                     uids, mids, EU, EM, W1, B1, W2, B2, W3, B3, out);
}